// Round 7
// baseline (1662.726 us; speedup 1.0000x reference)
//
#include <hip/hip_runtime.h>

#define NN 30000
#define NE 120000
#define NG 938   // ceil(NN/32)
#define TPB 256

__device__ __forceinline__ float blo(unsigned u) { return __uint_as_float(u << 16); }
__device__ __forceinline__ float bhi(unsigned u) { return __uint_as_float(u & 0xffff0000u); }

__global__ void k_zero(int* __restrict__ cnt) {
  int n = blockIdx.x * TPB + threadIdx.x;
  if (n < NN) cnt[n] = 0;
}

// kc[e*8+k] = relu(ea@k_w1+k_b1); cnt[dst]++
__global__ void k_prep(const float* __restrict__ ea, const float* __restrict__ w1,
                       const float* __restrict__ b1, const int* __restrict__ dst,
                       float* __restrict__ kc, int* __restrict__ cnt) {
  int e = blockIdx.x * TPB + threadIdx.x;
  if (e >= NE) return;
  float a[6];
#pragma unroll
  for (int i = 0; i < 6; i++) a[i] = ea[e * 6 + i];
#pragma unroll
  for (int k = 0; k < 8; k++) {
    float s = b1[k];
#pragma unroll
    for (int i = 0; i < 6; i++) s = fmaf(a[i], w1[i * 8 + k], s);
    kc[e * 8 + k] = fmaxf(s, 0.f);
  }
  atomicAdd(&cnt[dst[e]], 1);
}

// single-block prefix scan: rowstart/wpos = exclusive prefix of cnt; icnt = 1/max(cnt,1)
__global__ void k_scan(const int* __restrict__ cnt, int* __restrict__ rowstart,
                       int* __restrict__ wpos, float* __restrict__ icnt) {
  __shared__ int S[1024];
  int t = threadIdx.x;
  int base = t * 30;
  int s = 0;
  for (int j = 0; j < 30; j++) {
    int n = base + j;
    if (n < NN) s += cnt[n];
  }
  S[t] = s;
  __syncthreads();
  for (int off = 1; off < 1024; off <<= 1) {
    int v = S[t] + ((t >= off) ? S[t - off] : 0);
    __syncthreads();
    S[t] = v;
    __syncthreads();
  }
  int pref = (t > 0) ? S[t - 1] : 0;
  for (int j = 0; j < 30; j++) {
    int n = base + j;
    if (n < NN) {
      int c = cnt[n];
      rowstart[n] = pref;
      wpos[n] = pref;
      icnt[n] = 1.f / (float)max(c, 1);
      pref += c;
    }
  }
}

// scatter edge payloads into dst-sorted slots: srcs[pos], kcs[pos*8..]
__global__ void k_scatter(const int* __restrict__ dst, const int* __restrict__ src,
                          const float* __restrict__ kc, int* __restrict__ wpos,
                          int* __restrict__ srcs, float* __restrict__ kcs) {
  int e = blockIdx.x * TPB + threadIdx.x;
  if (e >= NE) return;
  int pos = atomicAdd(&wpos[dst[e]], 1);
  srcs[pos] = src[e];
  float4 a = *(const float4*)&kc[e * 8];
  float4 b = *(const float4*)&kc[e * 8 + 4];
  *(float4*)&kcs[(size_t)pos * 8] = a;
  *(float4*)&kcs[(size_t)pos * 8 + 4] = b;
}

__device__ __forceinline__ unsigned short f2b(float f) {
  unsigned u = __float_as_uint(f);
  return (unsigned short)((u + 0x7fff + ((u >> 16) & 1)) >> 16);  // RNE
}

// CSR aggregate for node n, lane o: acc = sum_edges( bias_row + sum_k ck_k * Pb4[s].k )
__device__ __forceinline__ float aggregate_node(
    int rs, int re, int o, const int* __restrict__ srcs,
    const float* __restrict__ kcs, const uint4* __restrict__ Pb4,
    const unsigned* __restrict__ Pb1) {
  float acc = 0.f;
  for (int j = rs; j < re; j++) {
    int s = srcs[j];
    float ck = (o < 8) ? kcs[(size_t)j * 8 + o] : 0.f;
    uint4 w = Pb4[(size_t)s * 32 + o];
    unsigned wb = Pb1[(size_t)s * 32 + o];
    acc += blo(wb);  // bias row, coefficient 1
    acc = fmaf(__shfl(ck, 0, 32), blo(w.x), acc);
    acc = fmaf(__shfl(ck, 1, 32), bhi(w.x), acc);
    acc = fmaf(__shfl(ck, 2, 32), blo(w.y), acc);
    acc = fmaf(__shfl(ck, 3, 32), bhi(w.y), acc);
    acc = fmaf(__shfl(ck, 4, 32), blo(w.z), acc);
    acc = fmaf(__shfl(ck, 5, 32), bhi(w.z), acc);
    acc = fmaf(__shfl(ck, 6, 32), blo(w.w), acc);
    acc = fmaf(__shfl(ck, 7, 32), bhi(w.w), acc);
  }
  return acc;
}

// 32-node transform, spill-free: no local arrays; LDS re-read per k-pair;
// incremental bf16 packing. Pb4 = k0..7 pairs, Pb1 = k8, Pr = root (f32).
__device__ __forceinline__ void transform32(const float* hL, const float* Wl,
                                            uint4* __restrict__ Pb4,
                                            unsigned* __restrict__ Pb1,
                                            float* __restrict__ Pr,
                                            int base, int tid) {
  const int g = tid >> 5, o = tid & 31, sw = (o & 7) << 2;
#pragma unroll
  for (int pp = 0; pp < 2; pp++) {
    const int ln0 = pp * 16 + g, ln1 = ln0 + 8;
    const int n0 = base + ln0, n1 = base + ln1;
    unsigned q0x = 0, q0y = 0, q0z = 0, q0w = 0;
    unsigned q1x = 0, q1y = 0, q1z = 0, q1w = 0;
#pragma unroll
    for (int kp = 0; kp < 4; kp++) {
      float aA0 = 0.f, aB0 = 0.f, aA1 = 0.f, aB1 = 0.f;
#pragma unroll
      for (int c = 0; c < 8; c++) {
        const float4 h0 = *(const float4*)&hL[ln0 * 32 + c * 4];
        const float4 h1 = *(const float4*)&hL[ln1 * 32 + c * 4];
        const int idx = o * 32 + ((c << 2) ^ sw);
        const float4 wA = *(const float4*)&Wl[(2 * kp) * 1024 + idx];
        const float4 wB = *(const float4*)&Wl[(2 * kp + 1) * 1024 + idx];
        aA0 = fmaf(h0.x, wA.x, aA0); aB0 = fmaf(h0.x, wB.x, aB0);
        aA1 = fmaf(h1.x, wA.x, aA1); aB1 = fmaf(h1.x, wB.x, aB1);
        aA0 = fmaf(h0.y, wA.y, aA0); aB0 = fmaf(h0.y, wB.y, aB0);
        aA1 = fmaf(h1.y, wA.y, aA1); aB1 = fmaf(h1.y, wB.y, aB1);
        aA0 = fmaf(h0.z, wA.z, aA0); aB0 = fmaf(h0.z, wB.z, aB0);
        aA1 = fmaf(h1.z, wA.z, aA1); aB1 = fmaf(h1.z, wB.z, aB1);
        aA0 = fmaf(h0.w, wA.w, aA0); aB0 = fmaf(h0.w, wB.w, aB0);
        aA1 = fmaf(h1.w, wA.w, aA1); aB1 = fmaf(h1.w, wB.w, aB1);
      }
      const unsigned p0 = f2b(aA0) | ((unsigned)f2b(aB0) << 16);
      const unsigned p1 = f2b(aA1) | ((unsigned)f2b(aB1) << 16);
      if (kp == 0)      { q0x = p0; q1x = p1; }
      else if (kp == 1) { q0y = p0; q1y = p1; }
      else if (kp == 2) { q0z = p0; q1z = p1; }
      else              { q0w = p0; q1w = p1; }
    }
    // k=8 (kernel bias row) and k=9 (root)
    float a80 = 0.f, a81 = 0.f, a90 = 0.f, a91 = 0.f;
#pragma unroll
    for (int c = 0; c < 8; c++) {
      const float4 h0 = *(const float4*)&hL[ln0 * 32 + c * 4];
      const float4 h1 = *(const float4*)&hL[ln1 * 32 + c * 4];
      const int idx = o * 32 + ((c << 2) ^ sw);
      const float4 w8 = *(const float4*)&Wl[8 * 1024 + idx];
      const float4 w9 = *(const float4*)&Wl[9 * 1024 + idx];
      a80 = fmaf(h0.x, w8.x, a80); a81 = fmaf(h1.x, w8.x, a81);
      a90 = fmaf(h0.x, w9.x, a90); a91 = fmaf(h1.x, w9.x, a91);
      a80 = fmaf(h0.y, w8.y, a80); a81 = fmaf(h1.y, w8.y, a81);
      a90 = fmaf(h0.y, w9.y, a90); a91 = fmaf(h1.y, w9.y, a91);
      a80 = fmaf(h0.z, w8.z, a80); a81 = fmaf(h1.z, w8.z, a81);
      a90 = fmaf(h0.z, w9.z, a90); a91 = fmaf(h1.z, w9.z, a91);
      a80 = fmaf(h0.w, w8.w, a80); a81 = fmaf(h1.w, w8.w, a81);
      a90 = fmaf(h0.w, w9.w, a90); a91 = fmaf(h1.w, w9.w, a91);
    }
    if (n0 < NN) {
      uint4 q; q.x = q0x; q.y = q0y; q.z = q0z; q.w = q0w;
      Pb4[(size_t)n0 * 32 + o] = q;
      Pb1[(size_t)n0 * 32 + o] = f2b(a80);
      Pr[(size_t)n0 * 32 + o] = a90;
    }
    if (n1 < NN) {
      uint4 q; q.x = q1x; q.y = q1y; q.z = q1z; q.w = q1w;
      Pb4[(size_t)n1 * 32 + o] = q;
      Pb1[(size_t)n1 * 32 + o] = f2b(a81);
      Pr[(size_t)n1 * 32 + o] = a91;
    }
  }
}

// MODE 0: h0 = fc1(x) -> transform.  MODE 1: CSR-aggregate -> h -> transform.
template <int MODE>
__global__ void k_layer(
    const float* __restrict__ x, const float* __restrict__ fc1w,
    const float* __restrict__ fc1b, const float* __restrict__ kw2,
    const float* __restrict__ kb2, const float* __restrict__ root,
    const float* __restrict__ cbias, const int* __restrict__ rowstart,
    const int* __restrict__ cnt, const float* __restrict__ icnt,
    const int* __restrict__ srcs, const float* __restrict__ kcs,
    const uint4* __restrict__ Pb4i, const unsigned* __restrict__ Pb1i,
    const float* __restrict__ Pri, uint4* __restrict__ Pb4o,
    unsigned* __restrict__ Pb1o, float* __restrict__ Pro) {
  __shared__ float Wl[10 * 1024];
  __shared__ float hL[1024];
  int tid = threadIdx.x;
  int base = blockIdx.x * 32;
  for (int f = tid; f < 10 * 1024; f += TPB) {
    int k = f >> 10, rem = f & 1023, i = rem >> 5, o = rem & 31;
    float v;
    if (f < 8192) v = kw2[f];
    else if (f < 9216) v = kb2[f - 8192];
    else v = root[f - 9216];
    Wl[(k * 1024 + o * 32 + i) ^ ((o & 7) << 2)] = v;
  }
  int g = tid >> 5, o = tid & 31;
  if (MODE == 0) {
    for (int e2 = tid; e2 < 1024; e2 += TPB) {
      int ln = e2 >> 5, oo = e2 & 31, n = base + ln;
      hL[e2] = (n < NN) ? fmaf(x[n], fc1w[oo], fc1b[oo]) : 0.f;
    }
  } else {
    for (int q = 0; q < 4; q++) {
      int ln = q * 8 + g;
      int n = base + ln;
      int rs = 0, re = 0;
      if (n < NN) { rs = rowstart[n]; re = rs + cnt[n]; }
      float acc = aggregate_node(rs, re, o, srcs, kcs, Pb4i, Pb1i);
      float h = 0.f;
      if (n < NN)
        h = fmaxf(fmaf(acc, icnt[n], Pri[(size_t)n * 32 + o] + cbias[o]), 0.f);
      hL[ln * 32 + o] = h;
    }
  }
  __syncthreads();
  transform32(hL, Wl, Pb4o, Pb1o, Pro, base, tid);
}

// final layer: aggregate -> h -> out = h @ fc2w + fc2b  (no LDS, high occupancy)
__global__ void k_final(const int* __restrict__ rowstart, const int* __restrict__ cnt,
                        const float* __restrict__ icnt, const int* __restrict__ srcs,
                        const float* __restrict__ kcs, const uint4* __restrict__ Pb4,
                        const unsigned* __restrict__ Pb1, const float* __restrict__ Pr,
                        const float* __restrict__ cbias, const float* __restrict__ fc2w,
                        const float* __restrict__ fc2b, float* __restrict__ out) {
  int t = blockIdx.x * TPB + threadIdx.x;
  int n = t >> 5, o = t & 31;
  if (n >= NN) return;
  int rs = rowstart[n], re = rs + cnt[n];
  float acc = aggregate_node(rs, re, o, srcs, kcs, Pb4, Pb1);
  float h = fmaxf(fmaf(acc, icnt[n], Pr[(size_t)n * 32 + o] + cbias[o]), 0.f);
  float s = h * fc2w[o];
#pragma unroll
  for (int d = 16; d; d >>= 1) s += __shfl_xor(s, d, 32);
  if (o == 0) out[n] = s + fc2b[0];
}

extern "C" void kernel_launch(void* const* d_in, const int* in_sizes, int n_in,
                              void* d_out, int out_size, void* d_ws, size_t ws_size,
                              hipStream_t stream) {
  const float* x     = (const float*)d_in[0];
  const int*   ei    = (const int*)d_in[1];
  const float* ea    = (const float*)d_in[2];
  const float* fc1w  = (const float*)d_in[3];
  const float* fc1b  = (const float*)d_in[4];
  const float* kw1   = (const float*)d_in[5];
  const float* kb1   = (const float*)d_in[6];
  const float* kw2   = (const float*)d_in[7];
  const float* kb2   = (const float*)d_in[8];
  const float* root  = (const float*)d_in[9];
  const float* cbias = (const float*)d_in[10];
  const float* fc2w  = (const float*)d_in[11];
  const float* fc2b  = (const float*)d_in[12];
  float* out = (float*)d_out;
  const int* srcp = ei;
  const int* dstp = ei + NE;

  float* ws = (float*)d_ws;
  float* kc       = ws;                        // NE*8
  float* kcs      = kc + NE * 8;               // NE*8
  int*   srcs     = (int*)(kcs + NE * 8);      // NE
  float* icnt     = (float*)(srcs + NE);       // NN
  float* Pr0      = icnt + NN;                 // NN*32
  float* Pr1      = Pr0 + NN * 32;             // NN*32
  int*   cnt      = (int*)(Pr1 + NN * 32);     // NN
  int*   rowstart = cnt + NN;                  // NN
  int*   wpos     = rowstart + NN;             // NN
  uint4* Pb4_0    = (uint4*)(wpos + NN);       // NN*32 uint4
  uint4* Pb4_1    = Pb4_0 + (size_t)NN * 32;   // NN*32 uint4
  unsigned* Pb1_0 = (unsigned*)(Pb4_1 + (size_t)NN * 32);  // NN*32
  unsigned* Pb1_1 = Pb1_0 + (size_t)NN * 32;                // NN*32

  k_zero<<<(NN + TPB - 1) / TPB, TPB, 0, stream>>>(cnt);
  k_prep<<<(NE + TPB - 1) / TPB, TPB, 0, stream>>>(ea, kw1, kb1, dstp, kc, cnt);
  k_scan<<<1, 1024, 0, stream>>>(cnt, rowstart, wpos, icnt);
  k_scatter<<<(NE + TPB - 1) / TPB, TPB, 0, stream>>>(dstp, srcp, kc, wpos, srcs, kcs);

  k_layer<0><<<NG, TPB, 0, stream>>>(x, fc1w, fc1b, kw2, kb2, root, cbias,
                                     rowstart, cnt, icnt, srcs, kcs,
                                     Pb4_0, Pb1_0, Pr0, Pb4_0, Pb1_0, Pr0);
  k_layer<1><<<NG, TPB, 0, stream>>>(x, fc1w, fc1b, kw2, kb2, root, cbias,
                                     rowstart, cnt, icnt, srcs, kcs,
                                     Pb4_0, Pb1_0, Pr0, Pb4_1, Pb1_1, Pr1);
  k_layer<1><<<NG, TPB, 0, stream>>>(x, fc1w, fc1b, kw2, kb2, root, cbias,
                                     rowstart, cnt, icnt, srcs, kcs,
                                     Pb4_1, Pb1_1, Pr1, Pb4_0, Pb1_0, Pr0);
  k_layer<1><<<NG, TPB, 0, stream>>>(x, fc1w, fc1b, kw2, kb2, root, cbias,
                                     rowstart, cnt, icnt, srcs, kcs,
                                     Pb4_0, Pb1_0, Pr0, Pb4_1, Pb1_1, Pr1);
  k_final<<<(NN * 32 + TPB - 1) / TPB, TPB, 0, stream>>>(
      rowstart, cnt, icnt, srcs, kcs, Pb4_1, Pb1_1, Pr1, cbias, fc2w, fc2b, out);
}

// Round 8
// 298.081 us; speedup vs baseline: 5.5781x; 5.5781x over previous
//
#include <hip/hip_runtime.h>

#define NN 30000
#define NE 120000
#define NG 938   // ceil(NN/32)
#define TPB 256

__device__ __forceinline__ float blo(unsigned u) { return __uint_as_float(u << 16); }
__device__ __forceinline__ float bhi(unsigned u) { return __uint_as_float(u & 0xffff0000u); }

__device__ __forceinline__ unsigned short f2b(float f) {
  unsigned u = __float_as_uint(f);
  return (unsigned short)((u + 0x7fff + ((u >> 16) & 1)) >> 16);  // RNE
}

__global__ void k_zero(int* __restrict__ cnt) {
  int n = blockIdx.x * TPB + threadIdx.x;
  if (n < NN) cnt[n] = 0;
}

// kc[e*8+k] = relu(ea@k_w1+k_b1); cnt[dst]++
__global__ void k_prep(const float* __restrict__ ea, const float* __restrict__ w1,
                       const float* __restrict__ b1, const int* __restrict__ dst,
                       float* __restrict__ kc, int* __restrict__ cnt) {
  int e = blockIdx.x * TPB + threadIdx.x;
  if (e >= NE) return;
  float a[6];
#pragma unroll
  for (int i = 0; i < 6; i++) a[i] = ea[e * 6 + i];
#pragma unroll
  for (int k = 0; k < 8; k++) {
    float s = b1[k];
#pragma unroll
    for (int i = 0; i < 6; i++) s = fmaf(a[i], w1[i * 8 + k], s);
    kc[e * 8 + k] = fmaxf(s, 0.f);
  }
  atomicAdd(&cnt[dst[e]], 1);
}

// single-block prefix scan: rowstart/wpos = exclusive prefix of cnt; icnt = 1/max(cnt,1)
__global__ void k_scan(const int* __restrict__ cnt, int* __restrict__ rowstart,
                       int* __restrict__ wpos, float* __restrict__ icnt) {
  __shared__ int S[1024];
  int t = threadIdx.x;
  int base = t * 30;
  int s = 0;
  for (int j = 0; j < 30; j++) {
    int n = base + j;
    if (n < NN) s += cnt[n];
  }
  S[t] = s;
  __syncthreads();
  for (int off = 1; off < 1024; off <<= 1) {
    int v = S[t] + ((t >= off) ? S[t - off] : 0);
    __syncthreads();
    S[t] = v;
    __syncthreads();
  }
  int pref = (t > 0) ? S[t - 1] : 0;
  for (int j = 0; j < 30; j++) {
    int n = base + j;
    if (n < NN) {
      int c = cnt[n];
      rowstart[n] = pref;
      wpos[n] = pref;
      icnt[n] = 1.f / (float)max(c, 1);
      pref += c;
    }
  }
}

// scatter edge payloads into dst-sorted slots: srcs[pos], kcs[pos*8..]
__global__ void k_scatter(const int* __restrict__ dst, const int* __restrict__ src,
                          const float* __restrict__ kc, int* __restrict__ wpos,
                          int* __restrict__ srcs, float* __restrict__ kcs) {
  int e = blockIdx.x * TPB + threadIdx.x;
  if (e >= NE) return;
  int pos = atomicAdd(&wpos[dst[e]], 1);
  srcs[pos] = src[e];
  float4 a = *(const float4*)&kc[e * 8];
  float4 b = *(const float4*)&kc[e * 8 + 4];
  *(float4*)&kcs[(size_t)pos * 8] = a;
  *(float4*)&kcs[(size_t)pos * 8 + 4] = b;
}

// Node transform only. P layout: Pb4u[n][kp][o] (kp=0..3, bf16 pair of k=2kp,2kp+1),
// Pb1[n][o] (k=8, kernel-MLP bias row), Pr[n][o] (root term, f32).
// launch_bounds(256,3): LDS caps at 3 blk/CU -> VGPR budget ~170; unroll-1 kp loop
// caps in-flight LDS loads at one iteration (16 float4) -> no spill.
template <int FIRST>
__global__ __launch_bounds__(TPB, 3) void k_node(
    const float* __restrict__ x, const float* __restrict__ fc1w,
    const float* __restrict__ fc1b, const float* __restrict__ h,
    const float* __restrict__ kw2, const float* __restrict__ kb2,
    const float* __restrict__ root, unsigned* __restrict__ Pb4u,
    unsigned* __restrict__ Pb1, float* __restrict__ Pr) {
  __shared__ float Wl[10 * 1024];
  __shared__ float hL[1024];
  const int tid = threadIdx.x;
  const int base = blockIdx.x * 32;
  for (int f = tid; f < 10 * 1024; f += TPB) {
    int k = f >> 10, rem = f & 1023, i = rem >> 5, o = rem & 31;
    float v;
    if (f < 8192) v = kw2[f];
    else if (f < 9216) v = kb2[f - 8192];
    else v = root[f - 9216];
    Wl[(k * 1024 + o * 32 + i) ^ ((o & 7) << 2)] = v;
  }
  for (int e2 = tid; e2 < 1024; e2 += TPB) {
    int ln = e2 >> 5, oo = e2 & 31, n = base + ln;
    float hv = 0.f;
    if (n < NN) hv = FIRST ? fmaf(x[n], fc1w[oo], fc1b[oo]) : h[n * 32 + oo];
    hL[e2] = hv;
  }
  __syncthreads();
  const int g = tid >> 5, o = tid & 31, sw = (o & 7) << 2;
#pragma unroll
  for (int pp = 0; pp < 2; pp++) {
    const int ln0 = pp * 16 + g, ln1 = ln0 + 8;
    const int n0 = base + ln0, n1 = base + ln1;
    float4 hv0[8], hv1[8];
#pragma unroll
    for (int c = 0; c < 8; c++) {
      hv0[c] = *(const float4*)&hL[ln0 * 32 + c * 4];
      hv1[c] = *(const float4*)&hL[ln1 * 32 + c * 4];
    }
#pragma unroll 1
    for (int kp = 0; kp < 5; kp++) {
      float aA0 = 0.f, aB0 = 0.f, aA1 = 0.f, aB1 = 0.f;
#pragma unroll
      for (int c = 0; c < 8; c++) {
        const int idx = o * 32 + ((c << 2) ^ sw);
        const float4 wA = *(const float4*)&Wl[(2 * kp) * 1024 + idx];
        const float4 wB = *(const float4*)&Wl[(2 * kp + 1) * 1024 + idx];
        aA0 = fmaf(hv0[c].x, wA.x, aA0); aA1 = fmaf(hv1[c].x, wA.x, aA1);
        aB0 = fmaf(hv0[c].x, wB.x, aB0); aB1 = fmaf(hv1[c].x, wB.x, aB1);
        aA0 = fmaf(hv0[c].y, wA.y, aA0); aA1 = fmaf(hv1[c].y, wA.y, aA1);
        aB0 = fmaf(hv0[c].y, wB.y, aB0); aB1 = fmaf(hv1[c].y, wB.y, aB1);
        aA0 = fmaf(hv0[c].z, wA.z, aA0); aA1 = fmaf(hv1[c].z, wA.z, aA1);
        aB0 = fmaf(hv0[c].z, wB.z, aB0); aB1 = fmaf(hv1[c].z, wB.z, aB1);
        aA0 = fmaf(hv0[c].w, wA.w, aA0); aA1 = fmaf(hv1[c].w, wA.w, aA1);
        aB0 = fmaf(hv0[c].w, wB.w, aB0); aB1 = fmaf(hv1[c].w, wB.w, aB1);
      }
      if (kp < 4) {
        if (n0 < NN)
          Pb4u[(size_t)n0 * 128 + kp * 32 + o] =
              f2b(aA0) | ((unsigned)f2b(aB0) << 16);
        if (n1 < NN)
          Pb4u[(size_t)n1 * 128 + kp * 32 + o] =
              f2b(aA1) | ((unsigned)f2b(aB1) << 16);
      } else {  // 2*kp = 8 -> bias row; 2*kp+1 = 9 -> root
        if (n0 < NN) {
          Pb1[(size_t)n0 * 32 + o] = f2b(aA0);
          Pr[(size_t)n0 * 32 + o] = aB0;
        }
        if (n1 < NN) {
          Pb1[(size_t)n1 * 32 + o] = f2b(aA1);
          Pr[(size_t)n1 * 32 + o] = aB1;
        }
      }
    }
  }
}

// CSR aggregate + activation. FINAL=0: writes h. FINAL=1: out = h @ fc2w + fc2b.
// No LDS, ~25 live regs -> cannot spill at any occupancy target.
template <int FINAL>
__global__ void k_agg(const int* __restrict__ rowstart, const int* __restrict__ cnt,
                      const float* __restrict__ icnt, const int* __restrict__ srcs,
                      const float* __restrict__ kcs,
                      const unsigned* __restrict__ Pb4u,
                      const unsigned* __restrict__ Pb1, const float* __restrict__ Pr,
                      const float* __restrict__ cbias, const float* __restrict__ fc2w,
                      const float* __restrict__ fc2b, float* __restrict__ h,
                      float* __restrict__ out) {
  int t = blockIdx.x * TPB + threadIdx.x;
  int n = t >> 5, o = t & 31;
  if (n >= NN) return;
  int rs = rowstart[n], re = rs + cnt[n];
  float acc = 0.f;
  for (int j = rs; j < re; j++) {
    int s = srcs[j];
    float ck = (o < 8) ? kcs[(size_t)j * 8 + o] : 0.f;
    const unsigned* Ps = Pb4u + (size_t)s * 128;
    unsigned w0 = Ps[o], w1 = Ps[32 + o], w2 = Ps[64 + o], w3 = Ps[96 + o];
    unsigned wb = Pb1[(size_t)s * 32 + o];
    acc += blo(wb);  // bias row, coefficient 1
    acc = fmaf(__shfl(ck, 0, 32), blo(w0), acc);
    acc = fmaf(__shfl(ck, 1, 32), bhi(w0), acc);
    acc = fmaf(__shfl(ck, 2, 32), blo(w1), acc);
    acc = fmaf(__shfl(ck, 3, 32), bhi(w1), acc);
    acc = fmaf(__shfl(ck, 4, 32), blo(w2), acc);
    acc = fmaf(__shfl(ck, 5, 32), bhi(w2), acc);
    acc = fmaf(__shfl(ck, 6, 32), blo(w3), acc);
    acc = fmaf(__shfl(ck, 7, 32), bhi(w3), acc);
  }
  float hv = fmaxf(fmaf(acc, icnt[n], Pr[(size_t)n * 32 + o] + cbias[o]), 0.f);
  if (FINAL) {
    float s2 = hv * fc2w[o];
#pragma unroll
    for (int d = 16; d; d >>= 1) s2 += __shfl_xor(s2, d, 32);
    if (o == 0) out[n] = s2 + fc2b[0];
  } else {
    h[(size_t)n * 32 + o] = hv;
  }
}

extern "C" void kernel_launch(void* const* d_in, const int* in_sizes, int n_in,
                              void* d_out, int out_size, void* d_ws, size_t ws_size,
                              hipStream_t stream) {
  const float* x     = (const float*)d_in[0];
  const int*   ei    = (const int*)d_in[1];
  const float* ea    = (const float*)d_in[2];
  const float* fc1w  = (const float*)d_in[3];
  const float* fc1b  = (const float*)d_in[4];
  const float* kw1   = (const float*)d_in[5];
  const float* kb1   = (const float*)d_in[6];
  const float* kw2   = (const float*)d_in[7];
  const float* kb2   = (const float*)d_in[8];
  const float* root  = (const float*)d_in[9];
  const float* cbias = (const float*)d_in[10];
  const float* fc2w  = (const float*)d_in[11];
  const float* fc2b  = (const float*)d_in[12];
  float* out = (float*)d_out;
  const int* srcp = ei;
  const int* dstp = ei + NE;

  float* ws = (float*)d_ws;
  float* kc       = ws;                        // NE*8
  float* kcs      = kc + NE * 8;               // NE*8
  int*   srcs     = (int*)(kcs + NE * 8);      // NE
  float* icnt     = (float*)(srcs + NE);       // NN
  float* h        = icnt + NN;                 // NN*32
  float* Pr       = h + NN * 32;               // NN*32
  int*   cnt      = (int*)(Pr + NN * 32);      // NN
  int*   rowstart = cnt + NN;                  // NN
  int*   wpos     = rowstart + NN;             // NN
  unsigned* Pb4u  = (unsigned*)(wpos + NN);    // NN*128
  unsigned* Pb1   = Pb4u + (size_t)NN * 128;   // NN*32

  k_zero<<<(NN + TPB - 1) / TPB, TPB, 0, stream>>>(cnt);
  k_prep<<<(NE + TPB - 1) / TPB, TPB, 0, stream>>>(ea, kw1, kb1, dstp, kc, cnt);
  k_scan<<<1, 1024, 0, stream>>>(cnt, rowstart, wpos, icnt);
  k_scatter<<<(NE + TPB - 1) / TPB, TPB, 0, stream>>>(dstp, srcp, kc, wpos, srcs, kcs);

  const int agg_grid = (NN * 32 + TPB - 1) / TPB;
  k_node<1><<<NG, TPB, 0, stream>>>(x, fc1w, fc1b, h, kw2, kb2, root, Pb4u, Pb1, Pr);
  for (int l = 0; l < 3; l++) {
    k_agg<0><<<agg_grid, TPB, 0, stream>>>(rowstart, cnt, icnt, srcs, kcs, Pb4u,
                                           Pb1, Pr, cbias, fc2w, fc2b, h, out);
    k_node<0><<<NG, TPB, 0, stream>>>(x, fc1w, fc1b, h, kw2, kb2, root, Pb4u, Pb1, Pr);
  }
  k_agg<1><<<agg_grid, TPB, 0, stream>>>(rowstart, cnt, icnt, srcs, kcs, Pb4u,
                                         Pb1, Pr, cbias, fc2w, fc2b, h, out);
}

// Round 9
// 228.724 us; speedup vs baseline: 7.2696x; 1.3032x over previous
//
#include <hip/hip_runtime.h>

#define NN 30000
#define NE 120000
#define NG 938   // ceil(NN/32)
#define TPB 256
#define SB 118   // ceil(NN/256) scan blocks

__device__ __forceinline__ float blo(unsigned u) { return __uint_as_float(u << 16); }
__device__ __forceinline__ float bhi(unsigned u) { return __uint_as_float(u & 0xffff0000u); }

__device__ __forceinline__ unsigned short f2b(float f) {
  unsigned u = __float_as_uint(f);
  return (unsigned short)((u + 0x7fff + ((u >> 16) & 1)) >> 16);  // RNE
}

__global__ void k_zero(int* __restrict__ cnt) {
  int n = blockIdx.x * TPB + threadIdx.x;
  if (n < NN) cnt[n] = 0;
}

// kc[e*8+k] = relu(ea@k_w1+k_b1); cnt[dst]++
__global__ void k_prep(const float* __restrict__ ea, const float* __restrict__ w1,
                       const float* __restrict__ b1, const int* __restrict__ dst,
                       float* __restrict__ kc, int* __restrict__ cnt) {
  int e = blockIdx.x * TPB + threadIdx.x;
  if (e >= NE) return;
  float a[6];
#pragma unroll
  for (int i = 0; i < 6; i++) a[i] = ea[e * 6 + i];
#pragma unroll
  for (int k = 0; k < 8; k++) {
    float s = b1[k];
#pragma unroll
    for (int i = 0; i < 6; i++) s = fmaf(a[i], w1[i * 8 + k], s);
    kc[e * 8 + k] = fmaxf(s, 0.f);
  }
  atomicAdd(&cnt[dst[e]], 1);
}

// 3-phase parallel scan (replaces the 78us single-block k_scan)
__global__ void k_scan1(const int* __restrict__ cnt, int* __restrict__ bsum) {
  __shared__ int S[TPB];
  int t = threadIdx.x, n = blockIdx.x * TPB + t;
  S[t] = (n < NN) ? cnt[n] : 0;
  __syncthreads();
  for (int off = TPB / 2; off; off >>= 1) {
    if (t < off) S[t] += S[t + off];
    __syncthreads();
  }
  if (t == 0) bsum[blockIdx.x] = S[0];
}

__global__ void k_scan2(int* __restrict__ bsum) {
  __shared__ int S[128];
  int t = threadIdx.x;
  S[t] = (t < SB) ? bsum[t] : 0;
  __syncthreads();
  for (int off = 1; off < 128; off <<= 1) {
    int v = S[t] + ((t >= off) ? S[t - off] : 0);
    __syncthreads();
    S[t] = v;
    __syncthreads();
  }
  if (t < SB) bsum[t] = (t > 0) ? S[t - 1] : 0;
}

__global__ void k_scan3(const int* __restrict__ cnt, const int* __restrict__ bsum,
                        int* __restrict__ rowstart, int* __restrict__ wpos,
                        float* __restrict__ icnt) {
  __shared__ int S[TPB];
  int t = threadIdx.x, n = blockIdx.x * TPB + t;
  int c = (n < NN) ? cnt[n] : 0;
  S[t] = c;
  __syncthreads();
  for (int off = 1; off < TPB; off <<= 1) {
    int v = S[t] + ((t >= off) ? S[t - off] : 0);
    __syncthreads();
    S[t] = v;
    __syncthreads();
  }
  if (n < NN) {
    int r = bsum[blockIdx.x] + S[t] - c;  // exclusive prefix
    rowstart[n] = r;
    wpos[n] = r;
    icnt[n] = 1.f / (float)max(c, 1);
  }
}

// scatter edge payloads into dst-sorted slots: srcs[pos], kcs[pos*8..]
__global__ void k_scatter(const int* __restrict__ dst, const int* __restrict__ src,
                          const float* __restrict__ kc, int* __restrict__ wpos,
                          int* __restrict__ srcs, float* __restrict__ kcs) {
  int e = blockIdx.x * TPB + threadIdx.x;
  if (e >= NE) return;
  int pos = atomicAdd(&wpos[dst[e]], 1);
  srcs[pos] = src[e];
  float4 a = *(const float4*)&kc[e * 8];
  float4 b = *(const float4*)&kc[e * 8 + 4];
  *(float4*)&kcs[(size_t)pos * 8] = a;
  *(float4*)&kcs[(size_t)pos * 8 + 4] = b;
}

// Node transform only (R8-verified, spill-free).
template <int FIRST>
__global__ __launch_bounds__(TPB, 3) void k_node(
    const float* __restrict__ x, const float* __restrict__ fc1w,
    const float* __restrict__ fc1b, const float* __restrict__ h,
    const float* __restrict__ kw2, const float* __restrict__ kb2,
    const float* __restrict__ root, unsigned* __restrict__ Pb4u,
    unsigned* __restrict__ Pb1, float* __restrict__ Pr) {
  __shared__ float Wl[10 * 1024];
  __shared__ float hL[1024];
  const int tid = threadIdx.x;
  const int base = blockIdx.x * 32;
  for (int f = tid; f < 10 * 1024; f += TPB) {
    int k = f >> 10, rem = f & 1023, i = rem >> 5, o = rem & 31;
    float v;
    if (f < 8192) v = kw2[f];
    else if (f < 9216) v = kb2[f - 8192];
    else v = root[f - 9216];
    Wl[(k * 1024 + o * 32 + i) ^ ((o & 7) << 2)] = v;
  }
  for (int e2 = tid; e2 < 1024; e2 += TPB) {
    int ln = e2 >> 5, oo = e2 & 31, n = base + ln;
    float hv = 0.f;
    if (n < NN) hv = FIRST ? fmaf(x[n], fc1w[oo], fc1b[oo]) : h[n * 32 + oo];
    hL[e2] = hv;
  }
  __syncthreads();
  const int g = tid >> 5, o = tid & 31, sw = (o & 7) << 2;
#pragma unroll
  for (int pp = 0; pp < 2; pp++) {
    const int ln0 = pp * 16 + g, ln1 = ln0 + 8;
    const int n0 = base + ln0, n1 = base + ln1;
    float4 hv0[8], hv1[8];
#pragma unroll
    for (int c = 0; c < 8; c++) {
      hv0[c] = *(const float4*)&hL[ln0 * 32 + c * 4];
      hv1[c] = *(const float4*)&hL[ln1 * 32 + c * 4];
    }
#pragma unroll 1
    for (int kp = 0; kp < 5; kp++) {
      float aA0 = 0.f, aB0 = 0.f, aA1 = 0.f, aB1 = 0.f;
#pragma unroll
      for (int c = 0; c < 8; c++) {
        const int idx = o * 32 + ((c << 2) ^ sw);
        const float4 wA = *(const float4*)&Wl[(2 * kp) * 1024 + idx];
        const float4 wB = *(const float4*)&Wl[(2 * kp + 1) * 1024 + idx];
        aA0 = fmaf(hv0[c].x, wA.x, aA0); aA1 = fmaf(hv1[c].x, wA.x, aA1);
        aB0 = fmaf(hv0[c].x, wB.x, aB0); aB1 = fmaf(hv1[c].x, wB.x, aB1);
        aA0 = fmaf(hv0[c].y, wA.y, aA0); aA1 = fmaf(hv1[c].y, wA.y, aA1);
        aB0 = fmaf(hv0[c].y, wB.y, aB0); aB1 = fmaf(hv1[c].y, wB.y, aB1);
        aA0 = fmaf(hv0[c].z, wA.z, aA0); aA1 = fmaf(hv1[c].z, wA.z, aA1);
        aB0 = fmaf(hv0[c].z, wB.z, aB0); aB1 = fmaf(hv1[c].z, wB.z, aB1);
        aA0 = fmaf(hv0[c].w, wA.w, aA0); aA1 = fmaf(hv1[c].w, wA.w, aA1);
        aB0 = fmaf(hv0[c].w, wB.w, aB0); aB1 = fmaf(hv1[c].w, wB.w, aB1);
      }
      if (kp < 4) {
        if (n0 < NN)
          Pb4u[(size_t)n0 * 128 + kp * 32 + o] =
              f2b(aA0) | ((unsigned)f2b(aB0) << 16);
        if (n1 < NN)
          Pb4u[(size_t)n1 * 128 + kp * 32 + o] =
              f2b(aA1) | ((unsigned)f2b(aB1) << 16);
      } else {  // 2*kp = 8 -> bias row; 2*kp+1 = 9 -> root
        if (n0 < NN) {
          Pb1[(size_t)n0 * 32 + o] = f2b(aA0);
          Pr[(size_t)n0 * 32 + o] = aB0;
        }
        if (n1 < NN) {
          Pb1[(size_t)n1 * 32 + o] = f2b(aA1);
          Pr[(size_t)n1 * 32 + o] = aB1;
        }
      }
    }
  }
}

// CSR aggregate + activation. FINAL=0: writes h. FINAL=1: out = h @ fc2w + fc2b.
template <int FINAL>
__global__ void k_agg(const int* __restrict__ rowstart, const int* __restrict__ cnt,
                      const float* __restrict__ icnt, const int* __restrict__ srcs,
                      const float* __restrict__ kcs,
                      const unsigned* __restrict__ Pb4u,
                      const unsigned* __restrict__ Pb1, const float* __restrict__ Pr,
                      const float* __restrict__ cbias, const float* __restrict__ fc2w,
                      const float* __restrict__ fc2b, float* __restrict__ h,
                      float* __restrict__ out) {
  int t = blockIdx.x * TPB + threadIdx.x;
  int n = t >> 5, o = t & 31;
  if (n >= NN) return;
  int rs = rowstart[n], re = rs + cnt[n];
  float acc = 0.f;
  for (int j = rs; j < re; j++) {
    int s = srcs[j];
    float ck = (o < 8) ? kcs[(size_t)j * 8 + o] : 0.f;
    const unsigned* Ps = Pb4u + (size_t)s * 128;
    unsigned w0 = Ps[o], w1 = Ps[32 + o], w2 = Ps[64 + o], w3 = Ps[96 + o];
    unsigned wb = Pb1[(size_t)s * 32 + o];
    acc += blo(wb);  // bias row, coefficient 1
    acc = fmaf(__shfl(ck, 0, 32), blo(w0), acc);
    acc = fmaf(__shfl(ck, 1, 32), bhi(w0), acc);
    acc = fmaf(__shfl(ck, 2, 32), blo(w1), acc);
    acc = fmaf(__shfl(ck, 3, 32), bhi(w1), acc);
    acc = fmaf(__shfl(ck, 4, 32), blo(w2), acc);
    acc = fmaf(__shfl(ck, 5, 32), bhi(w2), acc);
    acc = fmaf(__shfl(ck, 6, 32), blo(w3), acc);
    acc = fmaf(__shfl(ck, 7, 32), bhi(w3), acc);
  }
  float hv = fmaxf(fmaf(acc, icnt[n], Pr[(size_t)n * 32 + o] + cbias[o]), 0.f);
  if (FINAL) {
    float s2 = hv * fc2w[o];
#pragma unroll
    for (int d = 16; d; d >>= 1) s2 += __shfl_xor(s2, d, 32);
    if (o == 0) out[n] = s2 + fc2b[0];
  } else {
    h[(size_t)n * 32 + o] = hv;
  }
}

extern "C" void kernel_launch(void* const* d_in, const int* in_sizes, int n_in,
                              void* d_out, int out_size, void* d_ws, size_t ws_size,
                              hipStream_t stream) {
  const float* x     = (const float*)d_in[0];
  const int*   ei    = (const int*)d_in[1];
  const float* ea    = (const float*)d_in[2];
  const float* fc1w  = (const float*)d_in[3];
  const float* fc1b  = (const float*)d_in[4];
  const float* kw1   = (const float*)d_in[5];
  const float* kb1   = (const float*)d_in[6];
  const float* kw2   = (const float*)d_in[7];
  const float* kb2   = (const float*)d_in[8];
  const float* root  = (const float*)d_in[9];
  const float* cbias = (const float*)d_in[10];
  const float* fc2w  = (const float*)d_in[11];
  const float* fc2b  = (const float*)d_in[12];
  float* out = (float*)d_out;
  const int* srcp = ei;
  const int* dstp = ei + NE;

  float* ws = (float*)d_ws;
  float* kc       = ws;                        // NE*8
  float* kcs      = kc + NE * 8;               // NE*8
  int*   srcs     = (int*)(kcs + NE * 8);      // NE
  float* icnt     = (float*)(srcs + NE);       // NN
  float* h        = icnt + NN;                 // NN*32
  float* Pr       = h + NN * 32;               // NN*32
  int*   cnt      = (int*)(Pr + NN * 32);      // NN
  int*   rowstart = cnt + NN;                  // NN
  int*   wpos     = rowstart + NN;             // NN
  int*   bsum     = wpos + NN;                 // SB
  unsigned* Pb4u  = (unsigned*)(bsum + 128);   // NN*128
  unsigned* Pb1   = Pb4u + (size_t)NN * 128;   // NN*32

  k_zero<<<(NN + TPB - 1) / TPB, TPB, 0, stream>>>(cnt);
  k_prep<<<(NE + TPB - 1) / TPB, TPB, 0, stream>>>(ea, kw1, kb1, dstp, kc, cnt);
  k_scan1<<<SB, TPB, 0, stream>>>(cnt, bsum);
  k_scan2<<<1, 128, 0, stream>>>(bsum);
  k_scan3<<<SB, TPB, 0, stream>>>(cnt, bsum, rowstart, wpos, icnt);
  k_scatter<<<(NE + TPB - 1) / TPB, TPB, 0, stream>>>(dstp, srcp, kc, wpos, srcs, kcs);

  const int agg_grid = (NN * 32 + TPB - 1) / TPB;
  k_node<1><<<NG, TPB, 0, stream>>>(x, fc1w, fc1b, h, kw2, kb2, root, Pb4u, Pb1, Pr);
  for (int l = 0; l < 3; l++) {
    k_agg<0><<<agg_grid, TPB, 0, stream>>>(rowstart, cnt, icnt, srcs, kcs, Pb4u,
                                           Pb1, Pr, cbias, fc2w, fc2b, h, out);
    k_node<0><<<NG, TPB, 0, stream>>>(x, fc1w, fc1b, h, kw2, kb2, root, Pb4u, Pb1, Pr);
  }
  k_agg<1><<<agg_grid, TPB, 0, stream>>>(rowstart, cnt, icnt, srcs, kcs, Pb4u,
                                         Pb1, Pr, cbias, fc2w, fc2b, h, out);
}